// Round 4
// baseline (58.076 us; speedup 1.0000x reference)
//
#include <hip/hip_runtime.h>
#include <hip/hip_fp16.h>
#include <cstdint>

#define BB 32
#define CC 256
#define HF 64
#define WF 64
#define MM 4096   // HF*WF
#define NN 64
#define MCHUNKS 32   // m-chunks per batch
#define MPB 128      // m per block (4 waves x 32)
#define KSTEPS 8     // 256 / 32

typedef _Float16 half8 __attribute__((ext_vector_type(8)));
typedef __fp16 fp16x2 __attribute__((ext_vector_type(2)));
typedef float f32x4 __attribute__((ext_vector_type(4)));

// ws layout:
//   wq   : _Float16[BB * 16384]            fragment-linear q-hat    (1 MB)
//   part : float[MCHUNKS][BB*NN][2]        (max, sumexp)            (512 KB)
//   trgl : float[BB*NN]
//   tidx : int[BB*NN]

// ---------------- phase 0: gather + l2-normalize queries ----------------
__global__ void phase0_gather_norm(const float* __restrict__ fs,
                                   const float* __restrict__ kps_src,
                                   const float* __restrict__ kps_trg,
                                   _Float16* __restrict__ wq,
                                   int* __restrict__ trgidx) {
  int blk = blockIdx.x;          // b*N + n
  int b = blk >> 6, n = blk & 63;
  int c = threadIdx.x;

  float kx = kps_src[blk * 2 + 0];
  float ky = kps_src[blk * 2 + 1];
  int fx = min(max((int)(kx * (1.0f / 16.0f)), 0), WF - 1);
  int fy = min(max((int)(ky * (1.0f / 16.0f)), 0), HF - 1);
  int pix = fy * WF + fx;

  float x = fs[((size_t)b * CC + c) * MM + pix];

  float v = x * x;
  #pragma unroll
  for (int off = 32; off >= 1; off >>= 1) v += __shfl_xor(v, off);
  __shared__ float ssum[4];
  int wid = c >> 6, lane = c & 63;
  if (lane == 0) ssum[wid] = v;
  __syncthreads();
  float tot = ssum[0] + ssum[1] + ssum[2] + ssum[3];
  float inv = 1.0f / fmaxf(sqrtf(tot), 1e-12f);

  // fragment-linear layout for mfma_f32_16x16x32_f16 A-operand:
  // lane l holds A[row=l&15][k=(l>>4)*8+j]; index = ((ks*4+nt)*64 + lane)*8 + j
  int ks = c >> 5, kg = (c >> 3) & 3, j = c & 7;
  int nt = n >> 4, nr = n & 15;
  int lane_f = kg * 16 + nr;
  size_t off = (size_t)b * 16384 + (size_t)((ks * 4 + nt) * 64 + lane_f) * 8 + j;
  wq[off] = (_Float16)(x * inv);

  if (c == 0) {
    float tx = kps_trg[blk * 2 + 0], ty = kps_trg[blk * 2 + 1];
    int gx = min(max((int)(tx * (1.0f / 16.0f)), 0), WF - 1);
    int gy = min(max((int)(ty * (1.0f / 16.0f)), 0), HF - 1);
    trgidx[blk] = gy * WF + gx;
  }
}

// ---------------- phase B: MFMA logits + online softmax partials --------
__global__ void __launch_bounds__(256, 4)
phaseB(const float* __restrict__ ft,
       const _Float16* __restrict__ wq,
       const int* __restrict__ tidx,
       float* __restrict__ part,
       float* __restrict__ trgl) {
  __shared__ _Float16 qf[16384];     // 32 KB: q-hat fragments for this b
  __shared__ int trg_lds[NN];
  __shared__ float pM[4 * NN], pS[4 * NN];

  int b = blockIdx.x >> 5, mc = blockIdx.x & 31;
  int tid = threadIdx.x;

  const uint4* src = (const uint4*)(wq + (size_t)b * 16384);
  uint4* dst = (uint4*)qf;
  #pragma unroll
  for (int i = 0; i < 8; ++i) dst[tid + 256 * i] = src[tid + 256 * i];
  if (tid < NN) trg_lds[tid] = tidx[b * NN + tid];
  __syncthreads();

  int w = tid >> 6, lane = tid & 63, g = lane >> 4, col = lane & 15;
  int m0 = mc * MPB + w * 32;        // this wave's first m
  const float* fb = ft + (size_t)b * CC * MM;
  const float* lb0 = fb + (size_t)(g * 8) * MM + (m0 + col);  // mt=0
  const float* lb1 = lb0 + 16;                                // mt=1

  f32x4 acc[4][2];
  #pragma unroll
  for (int nt = 0; nt < 4; ++nt)
    #pragma unroll
    for (int mt = 0; mt < 2; ++mt) acc[nt][mt] = (f32x4){0.f, 0.f, 0.f, 0.f};
  float ss0 = 0.f, ss1 = 0.f;

  const half8* qv = (const half8*)qf;

  // software-pipelined over k-tiles: prefetch next 16 f32 while computing
  float cur0[8], cur1[8], nxt0[8], nxt1[8];
  #pragma unroll
  for (int j = 0; j < 8; ++j) {
    cur0[j] = lb0[(size_t)j * MM];
    cur1[j] = lb1[(size_t)j * MM];
  }

  #pragma unroll
  for (int ks = 0; ks < KSTEPS; ++ks) {
    if (ks + 1 < KSTEPS) {
      #pragma unroll
      for (int j = 0; j < 8; ++j) {
        nxt0[j] = lb0[(size_t)((ks + 1) * 32 + j) * MM];
        nxt1[j] = lb1[(size_t)((ks + 1) * 32 + j) * MM];
      }
    }

    half8 a0 = qv[(ks * 4 + 0) * 64 + lane];
    half8 a1 = qv[(ks * 4 + 1) * 64 + lane];
    half8 a2 = qv[(ks * 4 + 2) * 64 + lane];
    half8 a3 = qv[(ks * 4 + 3) * 64 + lane];

    half8 b0, b1;
    #pragma unroll
    for (int j = 0; j < 4; ++j) {
      ss0 += cur0[2 * j] * cur0[2 * j] + cur0[2 * j + 1] * cur0[2 * j + 1];
      ss1 += cur1[2 * j] * cur1[2 * j] + cur1[2 * j + 1] * cur1[2 * j + 1];
      fp16x2 h0 = __builtin_amdgcn_cvt_pkrtz(cur0[2 * j], cur0[2 * j + 1]);
      fp16x2 h1 = __builtin_amdgcn_cvt_pkrtz(cur1[2 * j], cur1[2 * j + 1]);
      b0[2 * j] = (_Float16)h0[0]; b0[2 * j + 1] = (_Float16)h0[1];
      b1[2 * j] = (_Float16)h1[0]; b1[2 * j + 1] = (_Float16)h1[1];
    }

    acc[0][0] = __builtin_amdgcn_mfma_f32_16x16x32_f16(a0, b0, acc[0][0], 0, 0, 0);
    acc[1][0] = __builtin_amdgcn_mfma_f32_16x16x32_f16(a1, b0, acc[1][0], 0, 0, 0);
    acc[2][0] = __builtin_amdgcn_mfma_f32_16x16x32_f16(a2, b0, acc[2][0], 0, 0, 0);
    acc[3][0] = __builtin_amdgcn_mfma_f32_16x16x32_f16(a3, b0, acc[3][0], 0, 0, 0);
    acc[0][1] = __builtin_amdgcn_mfma_f32_16x16x32_f16(a0, b1, acc[0][1], 0, 0, 0);
    acc[1][1] = __builtin_amdgcn_mfma_f32_16x16x32_f16(a1, b1, acc[1][1], 0, 0, 0);
    acc[2][1] = __builtin_amdgcn_mfma_f32_16x16x32_f16(a2, b1, acc[2][1], 0, 0, 0);
    acc[3][1] = __builtin_amdgcn_mfma_f32_16x16x32_f16(a3, b1, acc[3][1], 0, 0, 0);

    #pragma unroll
    for (int j = 0; j < 8; ++j) { cur0[j] = nxt0[j]; cur1[j] = nxt1[j]; }
  }

  // total sumsq for this lane's m columns (groups hold disjoint c-subsets)
  ss0 += __shfl_xor(ss0, 16); ss0 += __shfl_xor(ss0, 32);
  ss1 += __shfl_xor(ss1, 16); ss1 += __shfl_xor(ss1, 32);
  float scale0 = 100.0f / fmaxf(sqrtf(ss0), 1e-12f);   // 1/(||f||*T)
  float scale1 = 100.0f / fmaxf(sqrtf(ss1), 1e-12f);

  int mA = m0 + col, mB = m0 + 16 + col;

  #pragma unroll
  for (int nt = 0; nt < 4; ++nt) {
    #pragma unroll
    for (int r = 0; r < 4; ++r) {
      int n = nt * 16 + g * 4 + r;
      float v0 = acc[nt][0][r] * scale0;
      float v1 = acc[nt][1][r] * scale1;
      int t = trg_lds[n];
      if (t == mA) trgl[b * NN + n] = v0;
      if (t == mB) trgl[b * NN + n] = v1;
      float mx = fmaxf(v0, v1);
      #pragma unroll
      for (int off = 8; off >= 1; off >>= 1) mx = fmaxf(mx, __shfl_xor(mx, off));
      float s = __expf(v0 - mx) + __expf(v1 - mx);
      #pragma unroll
      for (int off = 8; off >= 1; off >>= 1) s += __shfl_xor(s, off);
      if (col == 0) { pM[w * NN + n] = mx; pS[w * NN + n] = s; }
    }
  }
  __syncthreads();

  if (tid < NN) {
    int n = tid;
    float gm = fmaxf(fmaxf(pM[n], pM[NN + n]), fmaxf(pM[2 * NN + n], pM[3 * NN + n]));
    float S = 0.f;
    #pragma unroll
    for (int ww = 0; ww < 4; ++ww)
      S += pS[ww * NN + n] * __expf(pM[ww * NN + n] - gm);
    // part layout: [mc][b*NN+n][2]  -> coalesced reads in reduce
    size_t o = ((size_t)mc * (BB * NN) + b * NN + n) * 2;
    part[o] = gm;
    part[o + 1] = S;
  }
}

// ---------------- fused reduce: lse + nll + masked mean -----------------
__global__ void __launch_bounds__(1024)
reduceAB(const float* __restrict__ part,
         const float* __restrict__ trgl,
         const void* __restrict__ maskp,
         float* __restrict__ out) {
  int tid = threadIdx.x;

  __shared__ int flagF, flagB;
  if (tid == 0) { flagF = 0; flagB = 0; }
  __syncthreads();

  const unsigned char* mb = (const unsigned char*)maskp;
  int lf = 0, lb = 0;
  for (int i = tid; i < BB * NN; i += 1024) {
    unsigned char v = mb[i];
    int r = i & 3;
    if (r == 3 && v == 0x3F) lf = 1;   // float32 1.0f pattern
    if (r != 0 && v != 0) lb = 1;      // nonzero off-word byte
  }
  if (lf) atomicOr(&flagF, 1);
  if (lb) atomicOr(&flagB, 1);
  __syncthreads();
  int layout = flagF ? 2 : (flagB ? 0 : 1);  // 2=float32, 0=uchar, 1=int32

  float lsum = 0.f, lcnt = 0.f;
  #pragma unroll
  for (int h = 0; h < 2; ++h) {
    int p = tid + h * 1024;
    float gm = -1e30f;
    #pragma unroll
    for (int c = 0; c < MCHUNKS; ++c)
      gm = fmaxf(gm, part[((size_t)c * (BB * NN) + p) * 2]);
    float S = 0.f;
    #pragma unroll
    for (int c = 0; c < MCHUNKS; ++c) {
      size_t o = ((size_t)c * (BB * NN) + p) * 2;
      S += part[o + 1] * __expf(part[o] - gm);
    }
    float nll = gm + logf(S) - trgl[p];

    float mval;
    if (layout == 2) mval = ((const float*)maskp)[p];
    else if (layout == 0) mval = (float)mb[p];
    else mval = (float)((const int*)maskp)[p];
    lsum += nll * mval;
    lcnt += mval;
  }

  #pragma unroll
  for (int off = 32; off >= 1; off >>= 1) {
    lsum += __shfl_xor(lsum, off);
    lcnt += __shfl_xor(lcnt, off);
  }
  __shared__ float sS[16], sC[16];
  int wid = tid >> 6, lane = tid & 63;
  if (lane == 0) { sS[wid] = lsum; sC[wid] = lcnt; }
  __syncthreads();
  if (tid == 0) {
    float s = 0.f, cn = 0.f;
    #pragma unroll
    for (int i = 0; i < 16; ++i) { s += sS[i]; cn += sC[i]; }
    out[0] = s / fmaxf(cn, 1.0f);
  }
}

extern "C" void kernel_launch(void* const* d_in, const int* in_sizes, int n_in,
                              void* d_out, int out_size, void* d_ws, size_t ws_size,
                              hipStream_t stream) {
  const float* fs   = (const float*)d_in[0];
  const float* ft   = (const float*)d_in[1];
  const float* ksrc = (const float*)d_in[2];
  const float* ktrg = (const float*)d_in[3];
  const void*  mask = d_in[4];
  float* out = (float*)d_out;

  _Float16* wq = (_Float16*)d_ws;                        // BB*16384 halfs
  float* part  = (float*)((char*)d_ws + (size_t)BB * 16384 * 2);
  float* trgl  = part + (size_t)MCHUNKS * BB * NN * 2;
  int* tidx    = (int*)(trgl + BB * NN);

  phase0_gather_norm<<<BB * NN, 256, 0, stream>>>(fs, ksrc, ktrg, wq, tidx);
  phaseB<<<BB * MCHUNKS, 256, 0, stream>>>(ft, wq, tidx, part, trgl);
  reduceAB<<<1, 1024, 0, stream>>>(part, trgl, mask, out);
}